// Round 10
// baseline (118.668 us; speedup 1.0000x reference)
//
#include <hip/hip_runtime.h>
#include <hip/hip_bf16.h>

#define NROWS 8192
#define NC 256
#define KTOP 5
#define GAMMA 1.0f
#define MARGIN 2.0f
#define NSPLIT 2     // targ splits (4096 rows each)
#define PREDB 64     // pred rows per block (2 pg x 32)
#define TCHUNK 128   // targ rows per LDS chunk
#define CHUNKS 32    // 4096 / 128
#define NSLOT (NSPLIT * 4)  // per-row partial slots: (split, tg)

typedef __bf16 bf16x8 __attribute__((ext_vector_type(8)));
typedef float f32x4 __attribute__((ext_vector_type(4)));
typedef _Float16 h2 __attribute__((ext_vector_type(2)));

// packed-f16 sorted-ascending top-5 insert (v_pk_max_f16 / v_pk_min_f16)
static __device__ __forceinline__ void ins5pk(h2 (&t)[KTOP], h2 v) {
    t[0] = __builtin_elementwise_max(t[0], __builtin_elementwise_min(v, t[1]));
    t[1] = __builtin_elementwise_max(t[1], __builtin_elementwise_min(v, t[2]));
    t[2] = __builtin_elementwise_max(t[2], __builtin_elementwise_min(v, t[3]));
    t[3] = __builtin_elementwise_max(t[3], __builtin_elementwise_min(v, t[4]));
    t[4] = __builtin_elementwise_max(t[4], v);
}

static __device__ __forceinline__ void ins5f(float (&t)[KTOP], float v) {
    t[0] = fmaxf(t[0], fminf(v, t[1]));
    t[1] = fmaxf(t[1], fminf(v, t[2]));
    t[2] = fmaxf(t[2], fminf(v, t[3]));
    t[3] = fmaxf(t[3], fminf(v, t[4]));
    t[4] = fmaxf(t[4], v);
}

// f32 pair -> packed f16 (v_cvt_pkrtz_f16_f32)
static __device__ __forceinline__ h2 pkrtz(float a, float b) {
    return __builtin_bit_cast(h2, __builtin_amdgcn_cvt_pkrtz(a, b));
}

// ---------------- Kernel A: row-normalize fp32 -> bf16 ----------------
__global__ __launch_bounds__(256) void norm_cast_kernel(
    const float* __restrict__ a, const float* __restrict__ b,
    unsigned short* __restrict__ an, unsigned short* __restrict__ bn) {
    const float* src = blockIdx.y ? b : a;
    unsigned short* dst = blockIdx.y ? bn : an;
    int row = blockIdx.x * 4 + (threadIdx.x >> 6);
    int lane = threadIdx.x & 63;
    float4 v = reinterpret_cast<const float4*>(src + (size_t)row * NC)[lane];
    float ss = v.x * v.x + v.y * v.y + v.z * v.z + v.w * v.w;
#pragma unroll
    for (int off = 32; off >= 1; off >>= 1) ss += __shfl_xor(ss, off);
    float inv = rsqrtf(ss);
    __hip_bfloat16 h0 = __float2bfloat16(v.x * inv);
    __hip_bfloat16 h1 = __float2bfloat16(v.y * inv);
    __hip_bfloat16 h2v = __float2bfloat16(v.z * inv);
    __hip_bfloat16 h3 = __float2bfloat16(v.w * inv);
    ushort4 o;
    o.x = __builtin_bit_cast(unsigned short, h0);
    o.y = __builtin_bit_cast(unsigned short, h1);
    o.z = __builtin_bit_cast(unsigned short, h2v);
    o.w = __builtin_bit_cast(unsigned short, h3);
    reinterpret_cast<ushort4*>(dst + (size_t)row * NC)[lane] = o;
}

// ------- Kernel B: fused sim GEMM + per-row running top-5 + diagonal -------
// grid = 256 (1/CU): 128 pred-blocks x 2 targ-splits. Block = 512 thr =
// 8 waves (2 pred-groups x 4 targ-groups). Per wave: 32 pred rows resident
// in 64 VGPRs. Targ streamed via 128 KB double-buffered LDS in 128-row
// chunks; 16B-slot XOR swizzle (slot ^= row&7) makes both ds_write and
// ds_read conflict-free (8 consecutive lanes hit 8 distinct 16B slots).
__global__ __launch_bounds__(512, 2) void simtop_kernel(
    const unsigned short* __restrict__ predn,
    const unsigned short* __restrict__ targn,
    float* __restrict__ diag, float* __restrict__ top5p) {
    __shared__ unsigned short tb[2][TCHUNK][NC];  // 2 x 64 KB

    int tid = threadIdx.x, w = tid >> 6, lane = tid & 63;
    int l15 = lane & 15, lq = lane >> 4;
    int bx = blockIdx.x;
    int split = bx & 1, bi = bx >> 1;
    int pg = w >> 2, tg = w & 3;
    int pgbase = bi * PREDB + pg * 32;  // wave's 32 pred cols
    int ts0 = split * (CHUNKS * TCHUNK);

    // resident pred fragments (B operand): 2 col-groups x 8 kk = 64 VGPR
    f32x4 pb0[8], pb1[8];
    {
        const unsigned short* pp = predn + (size_t)(pgbase + l15) * NC + lq * 8;
#pragma unroll
        for (int kk = 0; kk < 8; ++kk) {
            pb0[kk] = *reinterpret_cast<const f32x4*>(pp + kk * 32);
            pb1[kk] = *reinterpret_cast<const f32x4*>(pp + 16 * NC + kk * 32);
        }
    }
#pragma unroll
    for (int kk = 0; kk < 8; ++kk)
        asm volatile("" : "+v"(pb0[kk]), "+v"(pb1[kk]));

    h2 t01[KTOP];
    h2 NEG = {(_Float16)-65504.f, (_Float16)-65504.f};
#pragma unroll
    for (int j = 0; j < KTOP; ++j) t01[j] = NEG;

    // diagonal bookkeeping: which (chunk, tg) slice of this split sees it
    bool dblk = (split == (bi >> 6));
    int doffs = bi * PREDB + pg * 32 - ts0;  // valid only when dblk
    int cdiag = doffs >> 7;
    int tgdiag = (doffs >> 5) & 3;

    const char* tgbase = (const char*)(targn + (size_t)ts0 * NC);

    f32x4 sreg[8];  // per-thread 128B staging (T14 issue-early)
#define STAGE_LOAD(c)                                                       \
    {                                                                       \
        const char* src_ = tgbase + (size_t)(c) * (TCHUNK * NC * 2);        \
        _Pragma("unroll") for (int it = 0; it < 8; ++it) sreg[it] =         \
            *reinterpret_cast<const f32x4*>(src_ + it * 8192 + tid * 16);   \
    }
    // 16B-slot swizzle: slot' = slot ^ (row&7); ushort offset = slot'*8
#define STAGE_STORE(pbuf)                                                   \
    {                                                                       \
        _Pragma("unroll") for (int it = 0; it < 8; ++it) {                  \
            int L_ = it * 8192 + tid * 16;                                  \
            int r_ = L_ >> 9, slot_ = (L_ >> 4) & 31;                       \
            *reinterpret_cast<f32x4*>(                                      \
                &tb[pbuf][r_][(slot_ ^ (r_ & 7)) << 3]) = sreg[it];         \
        }                                                                   \
    }

    STAGE_LOAD(0);
    STAGE_STORE(0);
    __syncthreads();

    int r0 = tg * 32 + l15, r1 = r0 + 16;  // wave's two targ row groups
    int sw0 = r0 & 7;                      // == r1 & 7

    for (int c = 0; c < CHUNKS; ++c) {
        int pbuf = c & 1;
        if (c + 1 < CHUNKS) STAGE_LOAD(c + 1);

        f32x4 z = {0.f, 0.f, 0.f, 0.f};
        f32x4 acc00 = z, acc01 = z, acc10 = z, acc11 = z;  // [cg][rg]
#pragma unroll
        for (int kk = 0; kk < 8; ++kk) {
            bf16x8 a0 = *reinterpret_cast<const bf16x8*>(
                &tb[pbuf][r0][(((kk << 2) + lq) ^ sw0) << 3]);
            bf16x8 a1 = *reinterpret_cast<const bf16x8*>(
                &tb[pbuf][r1][(((kk << 2) + lq) ^ sw0) << 3]);
            acc00 = __builtin_amdgcn_mfma_f32_16x16x32_bf16(
                a0, __builtin_bit_cast(bf16x8, pb0[kk]), acc00, 0, 0, 0);
            acc10 = __builtin_amdgcn_mfma_f32_16x16x32_bf16(
                a0, __builtin_bit_cast(bf16x8, pb1[kk]), acc10, 0, 0, 0);
            acc01 = __builtin_amdgcn_mfma_f32_16x16x32_bf16(
                a1, __builtin_bit_cast(bf16x8, pb0[kk]), acc01, 0, 0, 0);
            acc11 = __builtin_amdgcn_mfma_f32_16x16x32_bf16(
                a1, __builtin_bit_cast(bf16x8, pb1[kk]), acc11, 0, 0, 0);
        }

        int trowbase = ts0 + c * TCHUNK + tg * 32;
        if (__builtin_expect(dblk && c == cdiag && tg == tgdiag, 0)) {
            int pc0 = pgbase + l15, pc1 = pgbase + 16 + l15;
#pragma unroll
            for (int rg = 0; rg < 2; ++rg)
#pragma unroll
                for (int j = 0; j < 4; ++j) {
                    int tr = trowbase + rg * 16 + lq * 4 + j;
                    float v0 = (rg ? acc01 : acc00)[j];
                    float v1 = (rg ? acc11 : acc10)[j];
                    if (tr == pc0) { diag[pc0] = v0; v0 = -65504.f; }
                    if (tr == pc1) { diag[pc1] = v1; v1 = -65504.f; }
                    ins5pk(t01, pkrtz(v0, v1));
                }
        } else {
#pragma unroll
            for (int rg = 0; rg < 2; ++rg)
#pragma unroll
                for (int j = 0; j < 4; ++j) {
                    float v0 = (rg ? acc01 : acc00)[j];
                    float v1 = (rg ? acc11 : acc10)[j];
                    ins5pk(t01, pkrtz(v0, v1));
                }
        }

        if (c + 1 < CHUNKS) STAGE_STORE(pbuf ^ 1);
        __syncthreads();
    }

    // merge the 4 lq-lanes holding the same pred cols (butterfly ^16, ^32)
#pragma unroll
    for (int m = 16; m <= 32; m <<= 1) {
        h2 pv[KTOP];
#pragma unroll
        for (int j = 0; j < KTOP; ++j) {
            int x = __shfl_xor(__builtin_bit_cast(int, t01[j]), m);
            pv[j] = __builtin_bit_cast(h2, x);
        }
#pragma unroll
        for (int j = 0; j < KTOP; ++j) ins5pk(t01, pv[j]);
    }

    if (lq == 0) {
        // per-(split, tg) partial slots — the 4 tg waves must NOT share a
        // slot (R9 bug: they raced, dropping 3/4 of the candidates)
        int slot = split * 4 + tg;
#pragma unroll
        for (int j = 0; j < KTOP; ++j) {
            float* base = top5p + (size_t)(slot * KTOP + j) * NROWS;
            base[pgbase + l15] = (float)t01[j].x;
            base[pgbase + 16 + l15] = (float)t01[j].y;
        }
    }
}

// ---------------- Kernel C: merge partials + loss reduction ----------------
__global__ __launch_bounds__(256) void finalize_kernel(
    const float* __restrict__ diag, const float* __restrict__ top5p,
    float* __restrict__ out) {
    int row = blockIdx.x * 256 + threadIdx.x;
    float t5[KTOP];
#pragma unroll
    for (int j = 0; j < KTOP; ++j) t5[j] = -1e30f;
#pragma unroll 8
    for (int sj = 0; sj < NSLOT * KTOP; ++sj)
        ins5f(t5, top5p[(size_t)sj * NROWS + row]);
    float d = diag[row];
    float sum = 0.f;
#pragma unroll
    for (int j = 0; j < KTOP; ++j)
        sum += fmaxf(t5[j] - GAMMA * d + MARGIN, 0.f);
#pragma unroll
    for (int off = 32; off >= 1; off >>= 1) sum += __shfl_xor(sum, off);
    __shared__ float red[4];
    int wv = threadIdx.x >> 6;
    if ((threadIdx.x & 63) == 0) red[wv] = sum;
    __syncthreads();
    if (threadIdx.x == 0) {
        float tot = red[0] + red[1] + red[2] + red[3];
        atomicAdd(out, tot * (1.0f / ((float)NROWS * KTOP)));
    }
}

extern "C" void kernel_launch(void* const* d_in, const int* in_sizes, int n_in,
                              void* d_out, int out_size, void* d_ws,
                              size_t ws_size, hipStream_t stream) {
    (void)in_sizes; (void)n_in; (void)out_size; (void)ws_size;
    const float* input = (const float*)d_in[0];
    const float* target = (const float*)d_in[1];
    char* ws = (char*)d_ws;
    unsigned short* predn = (unsigned short*)ws;                       // 4 MB
    unsigned short* targn = (unsigned short*)(ws + (size_t)NROWS * NC * 2);
    float* diag = (float*)(ws + (size_t)NROWS * NC * 4);               // 32 KB
    float* top5p = (float*)(ws + (size_t)NROWS * NC * 4 + NROWS * 4);  // 1.3 MB
    float* out = (float*)d_out;

    (void)hipMemsetAsync(d_out, 0, sizeof(float), stream);

    dim3 gA(NROWS / 4, 2);
    norm_cast_kernel<<<gA, 256, 0, stream>>>(input, target, predn, targn);

    simtop_kernel<<<256, 512, 0, stream>>>(predn, targn, diag, top5p);

    finalize_kernel<<<NROWS / 256, 256, 0, stream>>>(diag, top5p, out);
}

// Round 11
// 118.117 us; speedup vs baseline: 1.0047x; 1.0047x over previous
//
#include <hip/hip_runtime.h>
#include <hip/hip_bf16.h>

#define NROWS 8192
#define NC 256
#define KTOP 5
#define GAMMA 1.0f
#define MARGIN 2.0f
#define NSPLIT 8     // targ splits (1024 rows each), one per XCD
#define PREDB 128    // pred rows per block (4 pg x 32)
#define TCHUNK 64    // targ rows per LDS chunk (2 tg x 32)
#define CHUNKS 16    // 1024 / 64
#define NSLOT (NSPLIT * 2)  // per-row partial slots: (split, tg)

typedef __bf16 bf16x8 __attribute__((ext_vector_type(8)));
typedef float f32x4 __attribute__((ext_vector_type(4)));
typedef _Float16 h2 __attribute__((ext_vector_type(2)));

// packed-f16 sorted-ascending top-5 insert (v_pk_max_f16 / v_pk_min_f16)
static __device__ __forceinline__ void ins5pk(h2 (&t)[KTOP], h2 v) {
    t[0] = __builtin_elementwise_max(t[0], __builtin_elementwise_min(v, t[1]));
    t[1] = __builtin_elementwise_max(t[1], __builtin_elementwise_min(v, t[2]));
    t[2] = __builtin_elementwise_max(t[2], __builtin_elementwise_min(v, t[3]));
    t[3] = __builtin_elementwise_max(t[3], __builtin_elementwise_min(v, t[4]));
    t[4] = __builtin_elementwise_max(t[4], v);
}

static __device__ __forceinline__ void ins5f(float (&t)[KTOP], float v) {
    t[0] = fmaxf(t[0], fminf(v, t[1]));
    t[1] = fmaxf(t[1], fminf(v, t[2]));
    t[2] = fmaxf(t[2], fminf(v, t[3]));
    t[3] = fmaxf(t[3], fminf(v, t[4]));
    t[4] = fmaxf(t[4], v);
}

// f32 pair -> packed f16 (v_cvt_pkrtz_f16_f32)
static __device__ __forceinline__ h2 pkrtz(float a, float b) {
    return __builtin_bit_cast(h2, __builtin_amdgcn_cvt_pkrtz(a, b));
}

// ---------------- Kernel A: row-normalize fp32 -> bf16 ----------------
__global__ __launch_bounds__(256) void norm_cast_kernel(
    const float* __restrict__ a, const float* __restrict__ b,
    unsigned short* __restrict__ an, unsigned short* __restrict__ bn) {
    const float* src = blockIdx.y ? b : a;
    unsigned short* dst = blockIdx.y ? bn : an;
    int row = blockIdx.x * 4 + (threadIdx.x >> 6);
    int lane = threadIdx.x & 63;
    float4 v = reinterpret_cast<const float4*>(src + (size_t)row * NC)[lane];
    float ss = v.x * v.x + v.y * v.y + v.z * v.z + v.w * v.w;
#pragma unroll
    for (int off = 32; off >= 1; off >>= 1) ss += __shfl_xor(ss, off);
    float inv = rsqrtf(ss);
    __hip_bfloat16 h0 = __float2bfloat16(v.x * inv);
    __hip_bfloat16 h1 = __float2bfloat16(v.y * inv);
    __hip_bfloat16 h2v = __float2bfloat16(v.z * inv);
    __hip_bfloat16 h3 = __float2bfloat16(v.w * inv);
    ushort4 o;
    o.x = __builtin_bit_cast(unsigned short, h0);
    o.y = __builtin_bit_cast(unsigned short, h1);
    o.z = __builtin_bit_cast(unsigned short, h2v);
    o.w = __builtin_bit_cast(unsigned short, h3);
    reinterpret_cast<ushort4*>(dst + (size_t)row * NC)[lane] = o;
}

// ------- Kernel B: fused sim GEMM + per-row running top-5 + diagonal -------
// grid = 512 (2/CU): 64 pred-blocks x 8 splits (split = id&7 -> one split
// per XCD; its 512 KB targ slice stays L2-resident). Block = 512 thr =
// 8 waves (4 pred-groups x 2 targ-groups); per wave 32 pred cols resident
// in 64 VGPRs. Targ streamed via 64 KB double-buffered LDS (2 blocks/CU,
// 16 waves/CU hide the LDS pipe). PREDB=128 halves LDS write replication
// vs PREDB=64.
__global__ __launch_bounds__(512, 4) void simtop_kernel(
    const unsigned short* __restrict__ predn,
    const unsigned short* __restrict__ targn,
    float* __restrict__ diag, float* __restrict__ top5p) {
    __shared__ unsigned short tb[2][TCHUNK][NC];  // 2 x 32 KB

    int tid = threadIdx.x, w = tid >> 6, lane = tid & 63;
    int l15 = lane & 15, lq = lane >> 4;
    int id = blockIdx.x;
    int split = id & 7, bi = id >> 3;   // 8 splits x 64 pred-blocks
    int pg = w >> 1, tg = w & 1;        // 4 pred-groups x 2 targ-groups
    int pgbase = bi * PREDB + pg * 32;  // wave's 32 pred cols
    int ts0 = split * (CHUNKS * TCHUNK);

    // resident pred fragments (B operand): 2 col-groups x 8 kk = 64 VGPR
    f32x4 pb0[8], pb1[8];
    {
        const unsigned short* pp = predn + (size_t)(pgbase + l15) * NC + lq * 8;
#pragma unroll
        for (int kk = 0; kk < 8; ++kk) {
            pb0[kk] = *reinterpret_cast<const f32x4*>(pp + kk * 32);
            pb1[kk] = *reinterpret_cast<const f32x4*>(pp + 16 * NC + kk * 32);
        }
    }
#pragma unroll
    for (int kk = 0; kk < 8; ++kk)
        asm volatile("" : "+v"(pb0[kk]), "+v"(pb1[kk]));

    h2 t01[KTOP];
    h2 NEG = {(_Float16)-65504.f, (_Float16)-65504.f};
#pragma unroll
    for (int j = 0; j < KTOP; ++j) t01[j] = NEG;

    // diagonal bookkeeping: which (chunk, tg) slice of this split sees it
    bool dblk = (split == (bi >> 3));
    int doffs = bi * PREDB + pg * 32 - ts0;  // valid only when dblk
    int cdiag = doffs >> 6;                  // chunk of 64 rows
    int tgdiag = (doffs >> 5) & 1;           // tg group of 32 rows

    const char* tgbase = (const char*)(targn + (size_t)ts0 * NC);

    f32x4 sreg[4];  // per-thread 64B staging (T14 issue-early)
#define STAGE_LOAD(c)                                                       \
    {                                                                       \
        const char* src_ = tgbase + (size_t)(c) * (TCHUNK * NC * 2);        \
        _Pragma("unroll") for (int it = 0; it < 4; ++it) sreg[it] =         \
            *reinterpret_cast<const f32x4*>(src_ + it * 8192 + tid * 16);   \
    }
    // 16B-slot swizzle: slot' = slot ^ (row&7); ushort offset = slot'*8
#define STAGE_STORE(pbuf)                                                   \
    {                                                                       \
        _Pragma("unroll") for (int it = 0; it < 4; ++it) {                  \
            int L_ = it * 8192 + tid * 16;                                  \
            int r_ = L_ >> 9, slot_ = (L_ >> 4) & 31;                       \
            *reinterpret_cast<f32x4*>(                                      \
                &tb[pbuf][r_][(slot_ ^ (r_ & 7)) << 3]) = sreg[it];         \
        }                                                                   \
    }

    STAGE_LOAD(0);
    STAGE_STORE(0);
    __syncthreads();

    int r0 = tg * 32 + l15, r1 = r0 + 16;  // wave's two targ row groups
    int sw0 = r0 & 7;                      // == r1 & 7

    for (int c = 0; c < CHUNKS; ++c) {
        int pbuf = c & 1;
        if (c + 1 < CHUNKS) STAGE_LOAD(c + 1);

        f32x4 z = {0.f, 0.f, 0.f, 0.f};
        f32x4 acc00 = z, acc01 = z, acc10 = z, acc11 = z;  // [cg][rg]
#pragma unroll
        for (int kk = 0; kk < 8; ++kk) {
            bf16x8 a0 = *reinterpret_cast<const bf16x8*>(
                &tb[pbuf][r0][(((kk << 2) + lq) ^ sw0) << 3]);
            bf16x8 a1 = *reinterpret_cast<const bf16x8*>(
                &tb[pbuf][r1][(((kk << 2) + lq) ^ sw0) << 3]);
            acc00 = __builtin_amdgcn_mfma_f32_16x16x32_bf16(
                a0, __builtin_bit_cast(bf16x8, pb0[kk]), acc00, 0, 0, 0);
            acc10 = __builtin_amdgcn_mfma_f32_16x16x32_bf16(
                a0, __builtin_bit_cast(bf16x8, pb1[kk]), acc10, 0, 0, 0);
            acc01 = __builtin_amdgcn_mfma_f32_16x16x32_bf16(
                a1, __builtin_bit_cast(bf16x8, pb0[kk]), acc01, 0, 0, 0);
            acc11 = __builtin_amdgcn_mfma_f32_16x16x32_bf16(
                a1, __builtin_bit_cast(bf16x8, pb1[kk]), acc11, 0, 0, 0);
        }

        int trowbase = ts0 + c * TCHUNK + tg * 32;
        if (__builtin_expect(dblk && c == cdiag && tg == tgdiag, 0)) {
            int pc0 = pgbase + l15, pc1 = pgbase + 16 + l15;
#pragma unroll
            for (int rg = 0; rg < 2; ++rg)
#pragma unroll
                for (int j = 0; j < 4; ++j) {
                    int tr = trowbase + rg * 16 + lq * 4 + j;
                    float v0 = (rg ? acc01 : acc00)[j];
                    float v1 = (rg ? acc11 : acc10)[j];
                    if (tr == pc0) { diag[pc0] = v0; v0 = -65504.f; }
                    if (tr == pc1) { diag[pc1] = v1; v1 = -65504.f; }
                    ins5pk(t01, pkrtz(v0, v1));
                }
        } else {
#pragma unroll
            for (int rg = 0; rg < 2; ++rg)
#pragma unroll
                for (int j = 0; j < 4; ++j) {
                    float v0 = (rg ? acc01 : acc00)[j];
                    float v1 = (rg ? acc11 : acc10)[j];
                    ins5pk(t01, pkrtz(v0, v1));
                }
        }

        if (c + 1 < CHUNKS) STAGE_STORE(pbuf ^ 1);
        __syncthreads();
    }

    // merge the 4 lq-lanes holding the same pred cols (butterfly ^16, ^32)
#pragma unroll
    for (int m = 16; m <= 32; m <<= 1) {
        h2 pv[KTOP];
#pragma unroll
        for (int j = 0; j < KTOP; ++j) {
            int x = __shfl_xor(__builtin_bit_cast(int, t01[j]), m);
            pv[j] = __builtin_bit_cast(h2, x);
        }
#pragma unroll
        for (int j = 0; j < KTOP; ++j) ins5pk(t01, pv[j]);
    }

    if (lq == 0) {
        // per-(split, tg) partial slots — tg waves must not share a slot
        int slot = split * 2 + tg;
#pragma unroll
        for (int j = 0; j < KTOP; ++j) {
            float* base = top5p + (size_t)(slot * KTOP + j) * NROWS;
            base[pgbase + l15] = (float)t01[j].x;
            base[pgbase + 16 + l15] = (float)t01[j].y;
        }
    }
}

// ---------------- Kernel C: merge partials + loss reduction ----------------
__global__ __launch_bounds__(256) void finalize_kernel(
    const float* __restrict__ diag, const float* __restrict__ top5p,
    float* __restrict__ out) {
    int row = blockIdx.x * 256 + threadIdx.x;
    float t5[KTOP];
#pragma unroll
    for (int j = 0; j < KTOP; ++j) t5[j] = -1e30f;
#pragma unroll 16
    for (int sj = 0; sj < NSLOT * KTOP; ++sj)
        ins5f(t5, top5p[(size_t)sj * NROWS + row]);
    float d = diag[row];
    float sum = 0.f;
#pragma unroll
    for (int j = 0; j < KTOP; ++j)
        sum += fmaxf(t5[j] - GAMMA * d + MARGIN, 0.f);
#pragma unroll
    for (int off = 32; off >= 1; off >>= 1) sum += __shfl_xor(sum, off);
    __shared__ float red[4];
    int wv = threadIdx.x >> 6;
    if ((threadIdx.x & 63) == 0) red[wv] = sum;
    __syncthreads();
    if (threadIdx.x == 0) {
        float tot = red[0] + red[1] + red[2] + red[3];
        atomicAdd(out, tot * (1.0f / ((float)NROWS * KTOP)));
    }
}

extern "C" void kernel_launch(void* const* d_in, const int* in_sizes, int n_in,
                              void* d_out, int out_size, void* d_ws,
                              size_t ws_size, hipStream_t stream) {
    (void)in_sizes; (void)n_in; (void)out_size; (void)ws_size;
    const float* input = (const float*)d_in[0];
    const float* target = (const float*)d_in[1];
    char* ws = (char*)d_ws;
    unsigned short* predn = (unsigned short*)ws;                       // 4 MB
    unsigned short* targn = (unsigned short*)(ws + (size_t)NROWS * NC * 2);
    float* diag = (float*)(ws + (size_t)NROWS * NC * 4);               // 32 KB
    float* top5p = (float*)(ws + (size_t)NROWS * NC * 4 + NROWS * 4);  // 2.6 MB
    float* out = (float*)d_out;

    (void)hipMemsetAsync(d_out, 0, sizeof(float), stream);

    dim3 gA(NROWS / 4, 2);
    norm_cast_kernel<<<gA, 256, 0, stream>>>(input, target, predn, targn);

    simtop_kernel<<<512, 512, 0, stream>>>(predn, targn, diag, top5p);

    finalize_kernel<<<NROWS / 256, 256, 0, stream>>>(diag, top5p, out);
}